// Round 16
// baseline (837.391 us; speedup 1.0000x reference)
//
#include <hip/hip_runtime.h>

#define BATCH 2
#define SEQLEN 4096
#define DM 2048
#define DIP 8512
#define DIPP 8576
#define DI 4096
#define DCC 4352
#define NH 64
#define HD 64
#define DSZ 128
#define CHK 128
#define NC 32
#define NBL (BATCH*SEQLEN)
#define LDP 136

typedef __attribute__((ext_vector_type(4))) float f32x4;
typedef __attribute__((ext_vector_type(8))) __bf16 bf16x8;
typedef __attribute__((ext_vector_type(8))) unsigned short us8;
typedef __attribute__((ext_vector_type(4))) unsigned short us4;

__device__ inline float bf2f(unsigned short u){ union{unsigned int i; float f;} v; v.i=((unsigned)u)<<16; return v.f; }
__device__ inline unsigned short f2bf(float f){ union{float f; unsigned int i;} v; v.f=f; unsigned r=(v.i + 0x7FFFu + ((v.i>>16)&1u))>>16; return (unsigned short)r; }

#define GLOAD_LDS16(gp, lp) __builtin_amdgcn_global_load_lds( \
    (const __attribute__((address_space(1))) void*)(gp), \
    (__attribute__((address_space(3))) void*)(lp), 16, 0, 0)

__global__ void beacon_kernel(float* __restrict__ out, float v)
{
    if (blockIdx.x == 0 && threadIdx.x == 0) out[0] = v;
}

// ---------------- merged prep: cast u->bf16 | transpose W_in | transpose W_out ----------------
__device__ inline void transpose_tile(const float* __restrict__ in, unsigned short* __restrict__ out,
                                      int R, int C, int bx, int by, int t)
{
    __shared__ float tile[64][65];
    const int c0 = bx*64, r0 = by*64;
    const int tx = t & 15, ty = t >> 4;
    if (c0 < C) {
        #pragma unroll
        for (int i = 0; i < 4; i++) {
            const int r = ty + i*16;
            const float4 v = *(const float4*)&in[(size_t)(r0+r)*C + c0 + tx*4];
            tile[r][tx*4+0]=v.x; tile[r][tx*4+1]=v.y; tile[r][tx*4+2]=v.z; tile[r][tx*4+3]=v.w;
        }
    } else {
        #pragma unroll
        for (int i = 0; i < 4; i++) {
            const int r = ty + i*16;
            tile[r][tx*4+0]=0.f; tile[r][tx*4+1]=0.f; tile[r][tx*4+2]=0.f; tile[r][tx*4+3]=0.f;
        }
    }
    __syncthreads();
    const int cl = t >> 3;
    const int rg = (t & 7) * 8;
    #pragma unroll
    for (int j = 0; j < 2; j++) {
        const int cc = cl + j*32;
        us8 o;
        #pragma unroll
        for (int e = 0; e < 8; e++) o[e] = f2bf(tile[rg+e][cc]);
        *(us8*)&out[(size_t)(c0+cc)*R + r0 + rg] = o;
    }
}

#define PREP_CAST 2048
#define PREP_TRA  (134*32)
#define PREP_TRB  (32*64)

__global__ __launch_bounds__(256) void prep_kernel(
    const float* __restrict__ u, unsigned short* __restrict__ u_bf,
    const float* __restrict__ W_in, unsigned short* __restrict__ winT,
    const float* __restrict__ W_out, unsigned short* __restrict__ woutT)
{
    const int bid = blockIdx.x;
    const int t = threadIdx.x;
    if (bid < PREP_CAST) {
        const size_t n = (size_t)NBL*DM;
        const size_t stride = (size_t)PREP_CAST * 256 * 8;
        for (size_t i = ((size_t)bid*256 + t)*8; i < n; i += stride) {
            float4 a = *(const float4*)&u[i];
            float4 b = *(const float4*)&u[i+4];
            us8 o;
            o[0]=f2bf(a.x); o[1]=f2bf(a.y); o[2]=f2bf(a.z); o[3]=f2bf(a.w);
            o[4]=f2bf(b.x); o[5]=f2bf(b.y); o[6]=f2bf(b.z); o[7]=f2bf(b.w);
            *(us8*)&u_bf[i] = o;
        }
    } else if (bid < PREP_CAST + PREP_TRA) {
        const int q = bid - PREP_CAST;
        transpose_tile(W_in, winT, DM, DIP, q % 134, q / 134, t);
    } else {
        const int q = bid - PREP_CAST - PREP_TRA;
        transpose_tile(W_out, woutT, DI, DM, q % 32, q / 32, t);
    }
}

// ============ 256x256 GEMM: all-frags-at-ph0, 2-tile-deep prefetch, vmcnt(8) ============
template<int EPI>
__global__ __launch_bounds__(512, 1) void gemm256(
    const unsigned short* __restrict__ A, const unsigned short* __restrict__ Bt,
    float* __restrict__ C, int K, int ldc, int Nmax,
    unsigned short* __restrict__ zbf, unsigned short* __restrict__ xbcbf,
    float* __restrict__ dtf, const float* __restrict__ dt_bias)
{
    __shared__ unsigned short L[65536];   // 128 KiB: [buf][A|B][half 128x64]
    const int m0 = blockIdx.x * 256;
    const int n0 = blockIdx.y * 256;
    const int tid = threadIdx.x;
    const int lane = tid & 63;
    const int wid  = tid >> 6;
    const int wm = wid >> 2, wn = wid & 3;
    const int lr  = lane & 15;
    const int lkg = (lane >> 4) * 8;
    const int srow = (wid << 4) + (lane >> 3);
    const int scol = ((lane & 7) ^ (lane >> 3)) << 3;      // pre-swizzled source col
    const int cs0 = lkg ^ ((lr & 7) << 3);                 // swizzled read col, ks=0
    const int cs1 = cs0 ^ 32;                              // ks=1
    const int nt = K >> 6;

    f32x4 acc[8][4];
    #pragma unroll
    for (int i=0;i<8;i++)
        #pragma unroll
        for (int j=0;j<4;j++) acc[i][j] = f32x4{0.f,0.f,0.f,0.f};

    auto stA = [&](int buf, int t, int h) {
        const unsigned short* g = A + (size_t)(m0 + h*128 + srow)*K + t*64 + scol;
        GLOAD_LDS16(g,               &L[buf*32768 + h*8192 + wid*1024]);
        GLOAD_LDS16(g + (size_t)8*K, &L[buf*32768 + h*8192 + wid*1024 + 512]);
    };
    auto stB = [&](int buf, int t, int h) {
        const int rr = n0 + h*128 + srow;
        const int r0 = (rr     > Nmax) ? Nmax : rr;
        const int r1 = (rr + 8 > Nmax) ? Nmax : rr + 8;
        GLOAD_LDS16(Bt + (size_t)r0*K + t*64 + scol, &L[buf*32768 + 16384 + h*8192 + wid*1024]);
        GLOAD_LDS16(Bt + (size_t)r1*K + t*64 + scol, &L[buf*32768 + 16384 + h*8192 + wid*1024 + 512]);
    };
    auto rdA = [&](int buf, int mq, int s, int ks) {
        const int rl = mq*32 + s*16 + lr;
        return *(const bf16x8*)&L[buf*32768 + wm*8192 + rl*64 + (ks ? cs1 : cs0)];
    };
    auto rdB = [&](int buf, int nf, int ks) {
        const int rl = (wn & 1)*64 + nf*16 + lr;
        return *(const bf16x8*)&L[buf*32768 + 16384 + (wn >> 1)*8192 + rl*64 + (ks ? cs1 : cs0)];
    };

    bf16x8 af[4][2][2], bfr[4][2];
#define MFMAG(MQ) do { \
    __builtin_amdgcn_s_setprio(1); \
    _Pragma("unroll") \
    for (int s=0;s<2;s++) { \
        _Pragma("unroll") \
        for (int nf=0;nf<4;nf++) { \
            acc[(MQ)*2+s][nf] = __builtin_amdgcn_mfma_f32_16x16x32_bf16(af[MQ][s][0], bfr[nf][0], acc[(MQ)*2+s][nf], 0,0,0); \
            acc[(MQ)*2+s][nf] = __builtin_amdgcn_mfma_f32_16x16x32_bf16(af[MQ][s][1], bfr[nf][1], acc[(MQ)*2+s][nf], 0,0,0); } } \
    __builtin_amdgcn_s_setprio(0); \
} while(0)
#define BAR asm volatile("s_barrier" ::: "memory")

    // prologue: tile0 (8 loads) then tile1 (8 loads); vmcnt(8) drains tile0.
    stA(0, 0, 0); stA(0, 0, 1); stB(0, 0, 0); stB(0, 0, 1);
    stA(1, 1, 0); stA(1, 1, 1); stB(1, 1, 0); stB(1, 1, 1);
    asm volatile("s_waitcnt vmcnt(8)" ::: "memory");
    BAR;

    #pragma unroll 1
    for (int t = 0; t < nt; ++t) {
        const int buf = t & 1;
        const int tp2 = (t + 2 < nt) ? t + 2 : nt - 1;
        // ph0: read ALL fragments of tile t (A 16 + B 8), prove complete, then barrier.
        #pragma unroll
        for (int mq=0;mq<4;mq++) {
            af[mq][0][0]=rdA(buf,mq,0,0); af[mq][0][1]=rdA(buf,mq,0,1);
            af[mq][1][0]=rdA(buf,mq,1,0); af[mq][1][1]=rdA(buf,mq,1,1);
        }
        #pragma unroll
        for (int nf=0;nf<4;nf++){ bfr[nf][0]=rdB(buf,nf,0); bfr[nf][1]=rdB(buf,nf,1); }
        asm volatile("s_waitcnt lgkmcnt(0)" ::: "memory");
        __builtin_amdgcn_sched_barrier(0);
        BAR;                           // buf fully read by ALL waves -> stages below are WAR-safe
        MFMAG(0);
        stA(buf, tp2, 0); stA(buf, tp2, 1);
        BAR;
        MFMAG(1);
        stB(buf, tp2, 0);
        BAR;
        MFMAG(2);
        stB(buf, tp2, 1);
        asm volatile("s_waitcnt vmcnt(8)" ::: "memory");   // t+1's loads (2 tiles old) complete
        BAR;
        MFMAG(3);
    }
#undef MFMAG
#undef BAR

    const int cr = (lane >> 4) * 4;
    const int cc = lane & 15;
    #pragma unroll
    for (int i=0;i<8;i++) {
        #pragma unroll
        for (int j=0;j<4;j++) {
            const int row = m0 + wm*128 + i*16 + cr;
            const int col = n0 + wn*64 + j*16 + cc;
            #pragma unroll
            for (int r=0;r<4;r++) {
                const float val = acc[i][j][r];
                const int rr = row + r;
                if (EPI == 0) {
                    C[(size_t)rr*ldc + col] = val;
                } else {
                    if (col < DI) {
                        zbf[(size_t)rr*DI + col] = f2bf(val);
                    } else if (col < DI + DCC) {
                        xbcbf[(size_t)rr*DCC + (col - DI)] = f2bf(val);
                    } else if (col < DI + DCC + NH) {
                        const int hh = col - (DI + DCC);
                        const float x = val + dt_bias[hh];
                        dtf[(size_t)rr*NH + hh] = (x > 20.f) ? x : log1pf(__expf(x));
                    }
                }
            }
        }
    }
}

// ------- fused conv1d(4)+bias+SiLU: h<64 -> x channels w/ transpose; h in [64,68) -> B/C; h=68 -> cum -------
__global__ __launch_bounds__(256) void conv_x_kernel(
    const unsigned short* __restrict__ xbc,
    const float* __restrict__ cw, const float* __restrict__ cb,
    unsigned short* __restrict__ xT,
    unsigned short* __restrict__ bcbf,
    const float* __restrict__ dtf, const float* __restrict__ A_log, float* __restrict__ cum)
{
    __shared__ float raw[67][68];
    __shared__ unsigned short ot[64][72];
    const int lt = blockIdx.x;             // b*64 + l-tile
    const int h  = blockIdx.y;
    const int b  = lt >> 6;
    const int l0 = (lt & 63) * 64;
    const int t = threadIdx.x;

    if (h == NH + 4) {                     // cum: per-chunk cumsum of dtf*A (16 blocks)
        const int idx = lt*256 + t;
        if (lt >= 16 || idx >= BATCH*NC*NH) return;
        const int hh = idx & 63;
        const int bc = idx >> 6;
        const float A = -__expf(A_log[hh]);
        float c = 0.f;
        const float* src = dtf + (size_t)bc*CHK*NH + hh;
        float* dst = cum + (size_t)bc*CHK*NH + hh;
        for (int i = 0; i < CHK; i++) { c += src[i*NH]*A; dst[i*NH] = c; }
        return;
    }

    if (h >= NH) {
        const int g4 = h - NH;             // 0..3
        #pragma unroll
        for (int j = 0; j < 2; j++) {
            const int u = t + j*256;
            const int l = u >> 3, pg = (u & 7)*8;
            const int ch0 = DI + g4*64 + pg;
            const int row = b*SEQLEN + l0 + l;
            float a[8];
            #pragma unroll
            for (int e=0;e<8;e++) a[e] = cb[ch0+e];
            #pragma unroll
            for (int k = 0; k < 4; k++) {
                if (l0 + l + k >= 3) {
                    us8 v = *(const us8*)&xbc[(size_t)(row + k - 3)*DCC + ch0];
                    #pragma unroll
                    for (int e=0;e<8;e++) a[e] += bf2f(v[e]) * cw[(ch0+e)*4 + k];
                }
            }
            us8 o;
            #pragma unroll
            for (int e=0;e<8;e++){ const float s = a[e]/(1.f+__expf(-a[e])); o[e]=f2bf(s); }
            *(us8*)&bcbf[(size_t)row*256 + g4*64 + pg] = o;
        }
        return;
    }

    for (int i = t; i < 536; i += 256) {   // 67 rows x 8 groups
        const int li = i >> 3, cg = (i & 7) * 8;
        const int l = l0 - 3 + li;
        us8 v;
        #pragma unroll
        for (int e = 0; e < 8; e++) v[e] = 0;
        if (l >= 0) v = *(const us8*)&xbc[(size_t)(b*SEQLEN + l)*DCC + h*64 + cg];
        #pragma unroll
        for (int e = 0; e < 8; e++) raw[li][cg+e] = bf2f(v[e]);
    }
    __syncthreads();
    #pragma unroll
    for (int j = 0; j < 16; j++) {
        const int i = t + j*256;
        const int l = i >> 6, p = i & 63;
        const int ch = h*64 + p;
        float a = cb[ch];
        #pragma unroll
        for (int k = 0; k < 4; k++) a += raw[l + k][p] * cw[ch*4 + k];
        a = a / (1.f + __expf(-a));
        ot[l][p] = f2bf(a);
    }
    __syncthreads();
    for (int i = t; i < 512; i += 256) {   // 64 p x 8 groups
        const int p = i >> 3, lg = (i & 7) * 8;
        us8 o;
        #pragma unroll
        for (int e = 0; e < 8; e++) o[e] = ot[lg + e][p];
        *(us8*)&xT[(size_t)((b*NH + h)*HD + p)*SEQLEN + l0 + lg] = o;
    }
}

// ---------------- SSM pass S: states = (x*w)^T @ B -> bf16 (BT in LDS, XW in regs) ----------------
__global__ __launch_bounds__(256, 4) void ssm_passS(
    const unsigned short* __restrict__ bcbf,
    const unsigned short* __restrict__ xT,
    const float* __restrict__ cumg,
    const float* __restrict__ dtfg,
    unsigned short* __restrict__ states)
{
    __shared__ unsigned short BT[128*LDP];   // B^T [n][l] -> output bounce
    __shared__ float w_s[128];

    const int blk = blockIdx.x;
    const int h = blk & 63;
    const int bc = blk >> 6;
    const int r0 = bc * CHK;
    const int t = threadIdx.x;
    const int lane = t & 63;
    const int wid = t >> 6;

    if (t < 128) {
        const float cl = cumg[(size_t)(r0+127)*NH + h];
        const float ci = cumg[(size_t)(r0+t)*NH + h];
        const float dt = dtfg[(size_t)(r0+t)*NH + h];
        w_s[t] = __expf(cl - ci) * dt;
    }
    for (int i = t; i < 2048; i += 256) {
        const int l = i >> 4, cg = (i & 15)*8;
        us8 v = *(const us8*)(bcbf + (size_t)(r0+l)*256 + cg);   // B row l
        #pragma unroll
        for (int e = 0; e < 8; e++) BT[(cg+e)*LDP + l] = v[e];
    }
    __syncthreads();

    const int lr = lane & 15;
    const int lkg = (lane >> 4)*8;
    const int wr = wid >> 1, wc = wid & 1;
    const int b = bc >> 5;
    const int li = (bc & 31) * CHK;
    const unsigned short* xb = xT + (size_t)((b*NH + h)*HD)*SEQLEN + li;

    f32x4 acc[2][4];
    #pragma unroll
    for (int i=0;i<2;i++)
        #pragma unroll
        for (int j=0;j<4;j++) acc[i][j] = f32x4{0.f,0.f,0.f,0.f};
    #pragma unroll
    for (int k = 0; k < 4; k++) {
        bf16x8 a[2], bfr[4];
        #pragma unroll
        for (int i=0;i<2;i++) {
            us8 xv = *(const us8*)(xb + (size_t)(wr*32 + i*16 + lr)*SEQLEN + k*32 + lkg);
            us8 aw;
            #pragma unroll
            for (int e=0;e<8;e++) aw[e] = f2bf(bf2f(xv[e]) * w_s[k*32 + lkg + e]);
            a[i] = __builtin_bit_cast(bf16x8, aw);
        }
        #pragma unroll
        for (int j=0;j<4;j++) bfr[j] = *(const bf16x8*)&BT[(wc*64 + j*16 + lr)*LDP + k*32 + lkg];
        #pragma unroll
        for (int i=0;i<2;i++)
            #pragma unroll
            for (int j=0;j<4;j++)
                acc[i][j] = __builtin_amdgcn_mfma_f32_16x16x32_bf16(a[i], bfr[j], acc[i][j], 0,0,0);
    }
    __syncthreads();   // all waves done reading BT
    const int cr = (lane >> 4)*4, cc = lane & 15;
    #pragma unroll
    for (int i=0;i<2;i++) {
        #pragma unroll
        for (int j=0;j<4;j++) {
            const int nn = wc*64 + j*16 + cc;
            #pragma unroll
            for (int r=0;r<4;r++) {
                const int pp = wr*32 + i*16 + cr + r;
                BT[pp*LDP + nn] = f2bf(acc[i][j][r]);
            }
        }
    }
    __syncthreads();
    unsigned short* sb = states + (size_t)blk * (HD*DSZ);
    for (int i = t; i < 1024; i += 256) {   // 64 rows x 16 us8 groups
        const int pp = i >> 4, g = (i & 15)*8;
        *(us8*)&sb[pp*DSZ + g] = *(const us8*)&BT[pp*LDP + g];
    }
}

// ---------------- inter-chunk scan (in-place, bf16 storage, fp32 carry) ----------------
__global__ void scan_kernel(unsigned short* __restrict__ states, const float* __restrict__ cumg)
{
    const int idx = blockIdx.x*256 + threadIdx.x;  // (b,h,p,n)
    const int n = idx & 127;
    const int p = (idx >> 7) & 63;
    const int h = (idx >> 13) & 63;
    const int b = idx >> 19;
    float carry = 0.f;
    for (int c = 0; c < NC; c++) {
        const size_t off = ((size_t)((b*NC + c)*NH + h))*(HD*DSZ) + p*DSZ + n;
        const float s = bf2f(states[off]);
        states[off] = f2bf(carry);
        const float atot = __expf(cumg[(size_t)((b*NC+c)*CHK + 127)*NH + h]);
        carry = atot*carry + s;
    }
}

// -------- SSM pass Y: C/M in LDS; B, prev, X direct global; D folded into M diagonal --------
__global__ __launch_bounds__(256, 3) void ssm_passY(
    const unsigned short* __restrict__ bcbf,
    const unsigned short* __restrict__ xT,
    const unsigned short* __restrict__ statesg,
    const float* __restrict__ cumg,
    const float* __restrict__ dtfg,
    const float* __restrict__ Dg,
    unsigned short* __restrict__ y)
{
    __shared__ unsigned short P1[128*LDP];   // C -> M -> y bounce
    __shared__ float cum_s[128], dtc_s[128];

    const int blk = blockIdx.x;
    const int h = blk & 63;
    const int bc = blk >> 6;
    const int r0 = bc * CHK;
    const int t = threadIdx.x;
    const int lane = t & 63;
    const int wid = t >> 6;

    if (t < 128) {
        cum_s[t] = cumg[(size_t)(r0+t)*NH + h];
        dtc_s[t] = dtfg[(size_t)(r0+t)*NH + h];
    }
    for (int i = t; i < 2048; i += 256) {
        const int l = i >> 4, cg = (i & 15)*8;
        *(us8*)&P1[l*LDP + cg] = *(const us8*)(bcbf + (size_t)(r0+l)*256 + 128 + cg);   // C
    }
    __syncthreads();

    const int lr = lane & 15;
    const int lkg = (lane >> 4)*8;
    const int wr = wid >> 1, wc = wid & 1;
    const int b = bc >> 5;
    const int li = (bc & 31) * CHK;
    const unsigned short* xb = xT + (size_t)((b*NH + h)*HD)*SEQLEN + li;
    const unsigned short* sb = statesg + (size_t)blk * (HD*DSZ);
    const unsigned short* bb = bcbf + (size_t)r0*256;

    // stage 1: acc1 = C@B^T, acc2 = C@prev^T (B/prev frags direct global)
    f32x4 acc1[4][4], acc2[4][2];
    #pragma unroll
    for (int i=0;i<4;i++) {
        #pragma unroll
        for (int j=0;j<4;j++) acc1[i][j] = f32x4{0.f,0.f,0.f,0.f};
        #pragma unroll
        for (int j=0;j<2;j++) acc2[i][j] = f32x4{0.f,0.f,0.f,0.f};
    }
    #pragma unroll
    for (int k = 0; k < 4; k++) {
        bf16x8 a[4], bfr[4], pv[2];
        #pragma unroll
        for (int i=0;i<4;i++) a[i] = *(const bf16x8*)&P1[(wr*64 + i*16 + lr)*LDP + k*32 + lkg];
        #pragma unroll
        for (int j=0;j<4;j++) bfr[j] = *(const bf16x8*)(bb + (size_t)(wc*64 + j*16 + lr)*256 + k*32 + lkg);
        #pragma unroll
        for (int j=0;j<2;j++) pv[j] = *(const bf16x8*)(sb + (size_t)(wc*32 + j*16 + lr)*DSZ + k*32 + lkg);
        #pragma unroll
        for (int i=0;i<4;i++) {
            #pragma unroll
            for (int j=0;j<4;j++)
                acc1[i][j] = __builtin_amdgcn_mfma_f32_16x16x32_bf16(a[i], bfr[j], acc1[i][j], 0,0,0);
            #pragma unroll
            for (int j=0;j<2;j++)
                acc2[i][j] = __builtin_amdgcn_mfma_f32_16x16x32_bf16(a[i], pv[j], acc2[i][j], 0,0,0);
        }
    }
    __syncthreads();
    // M = CB * decay * dt (+ D on the diagonal) into P1
    const float Dv = Dg[h];
    const int cr = (lane >> 4)*4, cc = lane & 15;
    #pragma unroll
    for (int i=0;i<4;i++) {
        #pragma unroll
        for (int j=0;j<4;j++) {
            const int jj = wc*64 + j*16 + cc;
            #pragma unroll
            for (int r=0;r<4;r++) {
                const int ii = wr*64 + i*16 + cr + r;
                float v = 0.f;
                if (jj <= ii) v = acc1[i][j][r] * __expf(cum_s[ii] - cum_s[jj]) * dtc_s[jj];
                if (jj == ii) v += Dv;
                P1[ii*LDP + jj] = f2bf(v);
            }
        }
    }
    __syncthreads();
    // scale Y_off rows by exp(cum_i)
    #pragma unroll
    for (int i=0;i<4;i++) {
        #pragma unroll
        for (int r=0;r<4;r++) {
            const int ii = wr*64 + i*16 + cr + r;
            const float sc = __expf(cum_s[ii]);
            #pragma unroll
            for (int j=0;j<2;j++) acc2[i][j][r] *= sc;
        }
    }
    // stage 2: acc2 += (M + D*I) @ X  (X frags direct global)
    #pragma unroll
    for (int k = 0; k < 4; k++) {
        bf16x8 a[4], x2[2];
        #pragma unroll
        for (int i=0;i<4;i++) a[i] = *(const bf16x8*)&P1[(wr*64 + i*16 + lr)*LDP + k*32 + lkg];
        #pragma unroll
        for (int j=0;j<2;j++) x2[j] = *(const bf16x8*)(xb + (size_t)(wc*32 + j*16 + lr)*SEQLEN + k*32 + lkg);
        #pragma unroll
        for (int i=0;i<4;i++)
            #pragma unroll
            for (int j=0;j<2;j++)
                acc2[i][j] = __builtin_amdgcn_mfma_f32_16x16x32_bf16(a[i], x2[j], acc2[i][j], 0,0,0);
    }
    __syncthreads();   // all waves done reading P1
    // bounce y-tile (128 rows x 64 cols) through P1
    #pragma unroll
    for (int i=0;i<4;i++) {
        #pragma unroll
        for (int j=0;j<2;j++) {
            const int pp = wc*32 + j*16 + cc;
            #pragma unroll
            for (int r=0;r<4;r++) {
                const int ii = wr*64 + i*16 + cr + r;
                P1[ii*LDP + pp] = f2bf(acc2[i][j][r]);
            }
        }
    }
    __syncthreads();
    for (int i = t; i < 1024; i += 256) {   // 128 rows x 8 us8 groups
        const int ii = i >> 3, g = (i & 7)*8;
        *(us8*)&y[(size_t)(r0+ii)*DI + h*64 + g] = *(const us8*)&P1[ii*LDP + g];
    }
}

// ---------------- gate (y * silu(z)) + RMSNorm -> bf16 ----------------
__global__ __launch_bounds__(256) void gate_rms_kernel(
    const unsigned short* __restrict__ y, const unsigned short* __restrict__ z,
    const float* __restrict__ nw, unsigned short* __restrict__ tbf)
{
    const int row = blockIdx.x;
    const int t = threadIdx.x;
    const int lane = t & 63, wid = t >> 6;
    float tv[16];
    float ss = 0.f;
    #pragma unroll
    for (int i = 0; i < 2; i++) {
        const int c = (i*256 + t)*8;
        const us8 yv = *(const us8*)&y[(size_t)row*DI + c];
        const us8 zv = *(const us8*)&z[(size_t)row*DI + c];
        #pragma unroll
        for (int e = 0; e < 8; e++) {
            const float fy = bf2f(yv[e]);
            const float fz = bf2f(zv[e]);
            const float v = fy * (fz / (1.f + __expf(-fz)));
            tv[i*8+e] = v;
            ss += v*v;
        }
    }
    #pragma unroll
    for (int o = 1; o < 64; o <<= 1) ss += __shfl_xor(ss, o, 64);
    __shared__ float red[4];
    if (lane == 0) red[wid] = ss;
    __syncthreads();
    const float rms = rsqrtf((red[0]+red[1]+red[2]+red[3]) * (1.f/DI) + 1e-5f);
    #pragma unroll
    for (int i = 0; i < 2; i++) {
        const int c = (i*256 + t)*8;
        us8 o;
        #pragma unroll
        for (int e = 0; e < 8; e += 4) {
            const float4 wv = *(const float4*)&nw[c + e];
            o[e+0]=f2bf(tv[i*8+e+0]*rms*wv.x);
            o[e+1]=f2bf(tv[i*8+e+1]*rms*wv.y);
            o[e+2]=f2bf(tv[i*8+e+2]*rms*wv.z);
            o[e+3]=f2bf(tv[i*8+e+3]*rms*wv.w);
        }
        *(us8*)&tbf[(size_t)row*DI + c] = o;
    }
}

extern "C" void kernel_launch(void* const* d_in, const int* in_sizes, int n_in,
                              void* d_out, int out_size, void* d_ws, size_t ws_size,
                              hipStream_t stream)
{
    const float* u       = (const float*)d_in[0];
    const float* W_in    = (const float*)d_in[1];
    const float* conv_w  = (const float*)d_in[2];
    const float* conv_b  = (const float*)d_in[3];
    const float* dt_bias = (const float*)d_in[4];
    const float* A_log   = (const float*)d_in[5];
    const float* Dp      = (const float*)d_in[6];
    const float* norm_w  = (const float*)d_in[7];
    const float* W_out   = (const float*)d_in[8];
    float* out = (float*)d_out;

    char* ws = (char*)d_ws;
    const size_t OFF_WINT = 33554432;
    const size_t OFF_R2   = 68681728;
    const size_t OFF_R3   = 139984896;   // states (64M)
    const size_t OFF_SM   = 207093760;   // dtf 2M | cum 2M | bc_bf 4M | woutT 16M
    const size_t NEED     = OFF_SM + 2097152 + 2097152 + 4194304 + 16777216;
    if (ws_size < NEED) {   // diagnostic beacon: absmax ~= 10000 + ws_size_MB
        beacon_kernel<<<1, 64, 0, stream>>>(out, 10000.f + (float)(ws_size >> 20));
        return;
    }

    unsigned short* u_bf   = (unsigned short*)(ws);
    unsigned short* winT   = (unsigned short*)(ws + OFF_WINT);
    unsigned short* xTb    = (unsigned short*)(ws);
    unsigned short* t_bf   = (unsigned short*)(ws);
    unsigned short* xbc_bf = (unsigned short*)(ws + OFF_R2);
    unsigned short* y_bf   = (unsigned short*)(ws + OFF_R2);
    unsigned short* states = (unsigned short*)(ws + OFF_R3);
    float*          dtf    = (float*)(ws + OFF_SM);
    float*          cum    = (float*)(ws + OFF_SM + 2097152);
    unsigned short* bc_bf  = (unsigned short*)(ws + OFF_SM + 4194304);
    unsigned short* woutT  = (unsigned short*)(ws + OFF_SM + 8388608);
    unsigned short* z_bf   = (unsigned short*)d_out;   // 64MB, exact fit

    prep_kernel<<<PREP_CAST + PREP_TRA + PREP_TRB, 256, 0, stream>>>(
        u, u_bf, W_in, winT, W_out, woutT);
    gemm256<1><<<dim3(NBL/256, (DIPP+255)/256), 512, 0, stream>>>(
        u_bf, winT, nullptr, DM, 0, DIPP-1, z_bf, xbc_bf, dtf, dt_bias);
    conv_x_kernel<<<dim3(NBL/64, NH+5), 256, 0, stream>>>(
        xbc_bf, conv_w, conv_b, xTb, bc_bf, dtf, A_log, cum);
    ssm_passS<<<BATCH*NC*NH, 256, 0, stream>>>(bc_bf, xTb, cum, dtf, states);
    scan_kernel<<<4096, 256, 0, stream>>>(states, cum);
    ssm_passY<<<BATCH*NC*NH, 256, 0, stream>>>(bc_bf, xTb, states, cum, dtf, Dp, y_bf);
    gate_rms_kernel<<<NBL, 256, 0, stream>>>(y_bf, z_bf, norm_w, t_bf);
    gemm256<0><<<dim3(NBL/256, DM/256), 512, 0, stream>>>(
        t_bf, woutT, out, DI, DM, DM-1, nullptr, nullptr, nullptr, nullptr);
}

// Round 17
// 818.329 us; speedup vs baseline: 1.0233x; 1.0233x over previous
//
#include <hip/hip_runtime.h>

#define BATCH 2
#define SEQLEN 4096
#define DM 2048
#define DIP 8512
#define DIPP 8576
#define DI 4096
#define DCC 4352
#define NH 64
#define HD 64
#define DSZ 128
#define CHK 128
#define NC 32
#define NBL (BATCH*SEQLEN)
#define LDP 136

typedef __attribute__((ext_vector_type(4))) float f32x4;
typedef __attribute__((ext_vector_type(8))) __bf16 bf16x8;
typedef __attribute__((ext_vector_type(8))) unsigned short us8;
typedef __attribute__((ext_vector_type(4))) unsigned short us4;

__device__ inline float bf2f(unsigned short u){ union{unsigned int i; float f;} v; v.i=((unsigned)u)<<16; return v.f; }
__device__ inline unsigned short f2bf(float f){ union{float f; unsigned int i;} v; v.f=f; unsigned r=(v.i + 0x7FFFu + ((v.i>>16)&1u))>>16; return (unsigned short)r; }

#define GLOAD_LDS16(gp, lp) __builtin_amdgcn_global_load_lds( \
    (const __attribute__((address_space(1))) void*)(gp), \
    (__attribute__((address_space(3))) void*)(lp), 16, 0, 0)

__global__ void beacon_kernel(float* __restrict__ out, float v)
{
    if (blockIdx.x == 0 && threadIdx.x == 0) out[0] = v;
}

// ---------------- merged prep: cast u->bf16 | transpose W_in | transpose W_out ----------------
__device__ inline void transpose_tile(const float* __restrict__ in, unsigned short* __restrict__ out,
                                      int R, int C, int bx, int by, int t)
{
    __shared__ float tile[64][65];
    const int c0 = bx*64, r0 = by*64;
    const int tx = t & 15, ty = t >> 4;
    if (c0 < C) {
        #pragma unroll
        for (int i = 0; i < 4; i++) {
            const int r = ty + i*16;
            const float4 v = *(const float4*)&in[(size_t)(r0+r)*C + c0 + tx*4];
            tile[r][tx*4+0]=v.x; tile[r][tx*4+1]=v.y; tile[r][tx*4+2]=v.z; tile[r][tx*4+3]=v.w;
        }
    } else {
        #pragma unroll
        for (int i = 0; i < 4; i++) {
            const int r = ty + i*16;
            tile[r][tx*4+0]=0.f; tile[r][tx*4+1]=0.f; tile[r][tx*4+2]=0.f; tile[r][tx*4+3]=0.f;
        }
    }
    __syncthreads();
    const int cl = t >> 3;
    const int rg = (t & 7) * 8;
    #pragma unroll
    for (int j = 0; j < 2; j++) {
        const int cc = cl + j*32;
        us8 o;
        #pragma unroll
        for (int e = 0; e < 8; e++) o[e] = f2bf(tile[rg+e][cc]);
        *(us8*)&out[(size_t)(c0+cc)*R + r0 + rg] = o;
    }
}

#define PREP_CAST 2048
#define PREP_TRA  (134*32)
#define PREP_TRB  (32*64)

__global__ __launch_bounds__(256) void prep_kernel(
    const float* __restrict__ u, unsigned short* __restrict__ u_bf,
    const float* __restrict__ W_in, unsigned short* __restrict__ winT,
    const float* __restrict__ W_out, unsigned short* __restrict__ woutT)
{
    const int bid = blockIdx.x;
    const int t = threadIdx.x;
    if (bid < PREP_CAST) {
        const size_t n = (size_t)NBL*DM;
        const size_t stride = (size_t)PREP_CAST * 256 * 8;
        for (size_t i = ((size_t)bid*256 + t)*8; i < n; i += stride) {
            float4 a = *(const float4*)&u[i];
            float4 b = *(const float4*)&u[i+4];
            us8 o;
            o[0]=f2bf(a.x); o[1]=f2bf(a.y); o[2]=f2bf(a.z); o[3]=f2bf(a.w);
            o[4]=f2bf(b.x); o[5]=f2bf(b.y); o[6]=f2bf(b.z); o[7]=f2bf(b.w);
            *(us8*)&u_bf[i] = o;
        }
    } else if (bid < PREP_CAST + PREP_TRA) {
        const int q = bid - PREP_CAST;
        transpose_tile(W_in, winT, DM, DIP, q % 134, q / 134, t);
    } else {
        const int q = bid - PREP_CAST - PREP_TRA;
        transpose_tile(W_out, woutT, DI, DM, q % 32, q / 32, t);
    }
}

// ============ 256x256 8-phase GEMM, R11 schedule (1 barrier/phase) ============
template<int EPI>
__global__ __launch_bounds__(512, 1) void gemm256(
    const unsigned short* __restrict__ A, const unsigned short* __restrict__ Bt,
    float* __restrict__ C, int K, int ldc, int Nmax,
    unsigned short* __restrict__ zbf, unsigned short* __restrict__ xbcbf,
    float* __restrict__ dtf, const float* __restrict__ dt_bias)
{
    __shared__ unsigned short L[65536];   // 128 KiB: [buf][A|B][half 128x64]
    const int m0 = blockIdx.x * 256;
    const int n0 = blockIdx.y * 256;
    const int tid = threadIdx.x;
    const int lane = tid & 63;
    const int wid  = tid >> 6;
    const int wm = wid >> 2, wn = wid & 3;
    const int lr  = lane & 15;
    const int lkg = (lane >> 4) * 8;
    const int srow = (wid << 4) + (lane >> 3);
    const int scol = ((lane & 7) ^ (lane >> 3)) << 3;      // pre-swizzled source col
    const int cs0 = lkg ^ ((lr & 7) << 3);                 // swizzled read col, ks=0
    const int cs1 = cs0 ^ 32;                              // ks=1
    const int nt = K >> 6;

    f32x4 acc[8][4];
    #pragma unroll
    for (int i=0;i<8;i++)
        #pragma unroll
        for (int j=0;j<4;j++) acc[i][j] = f32x4{0.f,0.f,0.f,0.f};

    auto stA = [&](int buf, int t, int h) {
        const unsigned short* g = A + (size_t)(m0 + h*128 + srow)*K + t*64 + scol;
        GLOAD_LDS16(g,               &L[buf*32768 + h*8192 + wid*1024]);
        GLOAD_LDS16(g + (size_t)8*K, &L[buf*32768 + h*8192 + wid*1024 + 512]);
    };
    auto stB = [&](int buf, int t, int h) {
        const int rr = n0 + h*128 + srow;
        const int r0 = (rr     > Nmax) ? Nmax : rr;
        const int r1 = (rr + 8 > Nmax) ? Nmax : rr + 8;
        GLOAD_LDS16(Bt + (size_t)r0*K + t*64 + scol, &L[buf*32768 + 16384 + h*8192 + wid*1024]);
        GLOAD_LDS16(Bt + (size_t)r1*K + t*64 + scol, &L[buf*32768 + 16384 + h*8192 + wid*1024 + 512]);
    };
    auto rdA = [&](int buf, int mq, int s, int ks) {
        const int rl = mq*32 + s*16 + lr;
        return *(const bf16x8*)&L[buf*32768 + wm*8192 + rl*64 + (ks ? cs1 : cs0)];
    };
    auto rdB = [&](int buf, int nf, int ks) {
        const int rl = (wn & 1)*64 + nf*16 + lr;
        return *(const bf16x8*)&L[buf*32768 + 16384 + (wn >> 1)*8192 + rl*64 + (ks ? cs1 : cs0)];
    };

    bf16x8 bfr[4][2];
#define PH(BUF, MQ, LOADB, ...) do { \
    bf16x8 af[2][2]; \
    af[0][0]=rdA(BUF,MQ,0,0); af[0][1]=rdA(BUF,MQ,0,1); \
    af[1][0]=rdA(BUF,MQ,1,0); af[1][1]=rdA(BUF,MQ,1,1); \
    if (LOADB) { \
        _Pragma("unroll") \
        for (int nf=0;nf<4;nf++){ bfr[nf][0]=rdB(BUF,nf,0); bfr[nf][1]=rdB(BUF,nf,1);} } \
    __VA_ARGS__; \
    asm volatile("s_barrier" ::: "memory"); \
    __builtin_amdgcn_s_setprio(1); \
    _Pragma("unroll") \
    for (int s=0;s<2;s++) { \
        _Pragma("unroll") \
        for (int nf=0;nf<4;nf++) { \
            acc[(MQ)*2+s][nf] = __builtin_amdgcn_mfma_f32_16x16x32_bf16(af[s][0], bfr[nf][0], acc[(MQ)*2+s][nf], 0,0,0); \
            acc[(MQ)*2+s][nf] = __builtin_amdgcn_mfma_f32_16x16x32_bf16(af[s][1], bfr[nf][1], acc[(MQ)*2+s][nf], 0,0,0); } } \
    __builtin_amdgcn_s_setprio(0); \
} while(0)

    // prologue: tile0 (A+B -> buf0) [8 loads], B(tile1) -> buf1 [4 loads];
    // vmcnt(4) drains tile0's 8, leaves B(t1) in flight.
    stA(0, 0, 0); stA(0, 0, 1); stB(0, 0, 0); stB(0, 0, 1);
    stB(1, 1, 0); stB(1, 1, 1);
    asm volatile("s_waitcnt vmcnt(4)" ::: "memory");
    asm volatile("s_barrier" ::: "memory");

    #pragma unroll 1
    for (int t = 0; t < nt; t += 2) {
        const int tp2 = (t + 2 < nt) ? t + 2 : nt - 1;
        const int tp3 = (t + 3 < nt) ? t + 3 : nt - 1;
        // tile t (buf0): A(t+1)->buf1 at ph0/1; B(t+2)->buf0 at ph2/3 (buf0-B dead after ph0)
        PH(0, 0, true,  stA(1, t+1, 0));
        PH(0, 1, false, stA(1, t+1, 1));
        PH(0, 2, false, stB(0, tp2, 0));
        PH(0, 3, false, stB(0, tp2, 1); asm volatile("s_waitcnt vmcnt(4)" ::: "memory"));
        // tile t+1 (buf1)
        PH(1, 0, true,  stA(0, tp2, 0));
        PH(1, 1, false, stA(0, tp2, 1));
        PH(1, 2, false, stB(1, tp3, 0));
        PH(1, 3, false, stB(1, tp3, 1); asm volatile("s_waitcnt vmcnt(4)" ::: "memory"));
    }
#undef PH

    const int cr = (lane >> 4) * 4;
    const int cc = lane & 15;
    #pragma unroll
    for (int i=0;i<8;i++) {
        #pragma unroll
        for (int j=0;j<4;j++) {
            const int row = m0 + wm*128 + i*16 + cr;
            const int col = n0 + wn*64 + j*16 + cc;
            #pragma unroll
            for (int r=0;r<4;r++) {
                const float val = acc[i][j][r];
                const int rr = row + r;
                if (EPI == 0) {
                    C[(size_t)rr*ldc + col] = val;
                } else {
                    if (col < DI) {
                        zbf[(size_t)rr*DI + col] = f2bf(val);
                    } else if (col < DI + DCC) {
                        xbcbf[(size_t)rr*DCC + (col - DI)] = f2bf(val);
                    } else if (col < DI + DCC + NH) {
                        const int hh = col - (DI + DCC);
                        const float x = val + dt_bias[hh];
                        dtf[(size_t)rr*NH + hh] = (x > 20.f) ? x : log1pf(__expf(x));
                    }
                }
            }
        }
    }
}

// ------- fused conv1d(4)+bias+SiLU: h<64 -> x channels w/ transpose; h in [64,68) -> B/C; h=68 -> cum -------
__global__ __launch_bounds__(256) void conv_x_kernel(
    const unsigned short* __restrict__ xbc,
    const float* __restrict__ cw, const float* __restrict__ cb,
    unsigned short* __restrict__ xT,
    unsigned short* __restrict__ bcbf,
    const float* __restrict__ dtf, const float* __restrict__ A_log, float* __restrict__ cum)
{
    __shared__ float raw[67][68];
    __shared__ unsigned short ot[64][72];
    const int lt = blockIdx.x;             // b*64 + l-tile
    const int h  = blockIdx.y;
    const int b  = lt >> 6;
    const int l0 = (lt & 63) * 64;
    const int t = threadIdx.x;

    if (h == NH + 4) {                     // cum: per-chunk cumsum of dtf*A (16 blocks)
        const int idx = lt*256 + t;
        if (lt >= 16 || idx >= BATCH*NC*NH) return;
        const int hh = idx & 63;
        const int bc = idx >> 6;
        const float A = -__expf(A_log[hh]);
        float c = 0.f;
        const float* src = dtf + (size_t)bc*CHK*NH + hh;
        float* dst = cum + (size_t)bc*CHK*NH + hh;
        for (int i = 0; i < CHK; i++) { c += src[i*NH]*A; dst[i*NH] = c; }
        return;
    }

    if (h >= NH) {
        const int g4 = h - NH;             // 0..3
        #pragma unroll
        for (int j = 0; j < 2; j++) {
            const int u = t + j*256;
            const int l = u >> 3, pg = (u & 7)*8;
            const int ch0 = DI + g4*64 + pg;
            const int row = b*SEQLEN + l0 + l;
            float a[8];
            #pragma unroll
            for (int e=0;e<8;e++) a[e] = cb[ch0+e];
            #pragma unroll
            for (int k = 0; k < 4; k++) {
                if (l0 + l + k >= 3) {
                    us8 v = *(const us8*)&xbc[(size_t)(row + k - 3)*DCC + ch0];
                    #pragma unroll
                    for (int e=0;e<8;e++) a[e] += bf2f(v[e]) * cw[(ch0+e)*4 + k];
                }
            }
            us8 o;
            #pragma unroll
            for (int e=0;e<8;e++){ const float s = a[e]/(1.f+__expf(-a[e])); o[e]=f2bf(s); }
            *(us8*)&bcbf[(size_t)row*256 + g4*64 + pg] = o;
        }
        return;
    }

    for (int i = t; i < 536; i += 256) {   // 67 rows x 8 groups
        const int li = i >> 3, cg = (i & 7) * 8;
        const int l = l0 - 3 + li;
        us8 v;
        #pragma unroll
        for (int e = 0; e < 8; e++) v[e] = 0;
        if (l >= 0) v = *(const us8*)&xbc[(size_t)(b*SEQLEN + l)*DCC + h*64 + cg];
        #pragma unroll
        for (int e = 0; e < 8; e++) raw[li][cg+e] = bf2f(v[e]);
    }
    __syncthreads();
    #pragma unroll
    for (int j = 0; j < 16; j++) {
        const int i = t + j*256;
        const int l = i >> 6, p = i & 63;
        const int ch = h*64 + p;
        float a = cb[ch];
        #pragma unroll
        for (int k = 0; k < 4; k++) a += raw[l + k][p] * cw[ch*4 + k];
        a = a / (1.f + __expf(-a));
        ot[l][p] = f2bf(a);
    }
    __syncthreads();
    for (int i = t; i < 512; i += 256) {   // 64 p x 8 groups
        const int p = i >> 3, lg = (i & 7) * 8;
        us8 o;
        #pragma unroll
        for (int e = 0; e < 8; e++) o[e] = ot[lg + e][p];
        *(us8*)&xT[(size_t)((b*NH + h)*HD + p)*SEQLEN + l0 + lg] = o;
    }
}

// ---------------- SSM pass S: states = (x*w)^T @ B -> bf16 (BT in LDS, XW in regs) ----------------
__global__ __launch_bounds__(256, 4) void ssm_passS(
    const unsigned short* __restrict__ bcbf,
    const unsigned short* __restrict__ xT,
    const float* __restrict__ cumg,
    const float* __restrict__ dtfg,
    unsigned short* __restrict__ states)
{
    __shared__ unsigned short BT[128*LDP];   // B^T [n][l] -> output bounce
    __shared__ float w_s[128];

    const int blk = blockIdx.x;
    const int h = blk & 63;
    const int bc = blk >> 6;
    const int r0 = bc * CHK;
    const int t = threadIdx.x;
    const int lane = t & 63;
    const int wid = t >> 6;

    if (t < 128) {
        const float cl = cumg[(size_t)(r0+127)*NH + h];
        const float ci = cumg[(size_t)(r0+t)*NH + h];
        const float dt = dtfg[(size_t)(r0+t)*NH + h];
        w_s[t] = __expf(cl - ci) * dt;
    }
    for (int i = t; i < 2048; i += 256) {
        const int l = i >> 4, cg = (i & 15)*8;
        us8 v = *(const us8*)(bcbf + (size_t)(r0+l)*256 + cg);   // B row l
        #pragma unroll
        for (int e = 0; e < 8; e++) BT[(cg+e)*LDP + l] = v[e];
    }
    __syncthreads();

    const int lr = lane & 15;
    const int lkg = (lane >> 4)*8;
    const int wr = wid >> 1, wc = wid & 1;
    const int b = bc >> 5;
    const int li = (bc & 31) * CHK;
    const unsigned short* xb = xT + (size_t)((b*NH + h)*HD)*SEQLEN + li;

    f32x4 acc[2][4];
    #pragma unroll
    for (int i=0;i<2;i++)
        #pragma unroll
        for (int j=0;j<4;j++) acc[i][j] = f32x4{0.f,0.f,0.f,0.f};
    #pragma unroll
    for (int k = 0; k < 4; k++) {
        bf16x8 a[2], bfr[4];
        #pragma unroll
        for (int i=0;i<2;i++) {
            us8 xv = *(const us8*)(xb + (size_t)(wr*32 + i*16 + lr)*SEQLEN + k*32 + lkg);
            us8 aw;
            #pragma unroll
            for (int e=0;e<8;e++) aw[e] = f2bf(bf2f(xv[e]) * w_s[k*32 + lkg + e]);
            a[i] = __builtin_bit_cast(bf16x8, aw);
        }
        #pragma unroll
        for (int j=0;j<4;j++) bfr[j] = *(const bf16x8*)&BT[(wc*64 + j*16 + lr)*LDP + k*32 + lkg];
        #pragma unroll
        for (int i=0;i<2;i++)
            #pragma unroll
            for (int j=0;j<4;j++)
                acc[i][j] = __builtin_amdgcn_mfma_f32_16x16x32_bf16(a[i], bfr[j], acc[i][j], 0,0,0);
    }
    __syncthreads();   // all waves done reading BT
    const int cr = (lane >> 4)*4, cc = lane & 15;
    #pragma unroll
    for (int i=0;i<2;i++) {
        #pragma unroll
        for (int j=0;j<4;j++) {
            const int nn = wc*64 + j*16 + cc;
            #pragma unroll
            for (int r=0;r<4;r++) {
                const int pp = wr*32 + i*16 + cr + r;
                BT[pp*LDP + nn] = f2bf(acc[i][j][r]);
            }
        }
    }
    __syncthreads();
    unsigned short* sb = states + (size_t)blk * (HD*DSZ);
    for (int i = t; i < 1024; i += 256) {   // 64 rows x 16 us8 groups
        const int pp = i >> 4, g = (i & 15)*8;
        *(us8*)&sb[pp*DSZ + g] = *(const us8*)&BT[pp*LDP + g];
    }
}

// ---------------- inter-chunk scan (in-place, bf16 storage, fp32 carry) ----------------
__global__ void scan_kernel(unsigned short* __restrict__ states, const float* __restrict__ cumg)
{
    const int idx = blockIdx.x*256 + threadIdx.x;  // (b,h,p,n)
    const int n = idx & 127;
    const int p = (idx >> 7) & 63;
    const int h = (idx >> 13) & 63;
    const int b = idx >> 19;
    float carry = 0.f;
    for (int c = 0; c < NC; c++) {
        const size_t off = ((size_t)((b*NC + c)*NH + h))*(HD*DSZ) + p*DSZ + n;
        const float s = bf2f(states[off]);
        states[off] = f2bf(carry);
        const float atot = __expf(cumg[(size_t)((b*NC+c)*CHK + 127)*NH + h]);
        carry = atot*carry + s;
    }
}

// -------- SSM pass Y: C/M in LDS; B, prev, X direct global; D folded into M diagonal --------
__global__ __launch_bounds__(256, 3) void ssm_passY(
    const unsigned short* __restrict__ bcbf,
    const unsigned short* __restrict__ xT,
    const unsigned short* __restrict__ statesg,
    const float* __restrict__ cumg,
    const float* __restrict__ dtfg,
    const float* __restrict__ Dg,
    unsigned short* __restrict__ y)
{
    __shared__ unsigned short P1[128*LDP];   // C -> M -> y bounce
    __shared__ float cum_s[128], dtc_s[128];

    const int blk = blockIdx.x;
    const int h = blk & 63;
    const int bc = blk >> 6;
    const int r0 = bc * CHK;
    const int t = threadIdx.x;
    const int lane = t & 63;
    const int wid = t >> 6;

    if (t < 128) {
        cum_s[t] = cumg[(size_t)(r0+t)*NH + h];
        dtc_s[t] = dtfg[(size_t)(r0+t)*NH + h];
    }
    for (int i = t; i < 2048; i += 256) {
        const int l = i >> 4, cg = (i & 15)*8;
        *(us8*)&P1[l*LDP + cg] = *(const us8*)(bcbf + (size_t)(r0+l)*256 + 128 + cg);   // C
    }
    __syncthreads();

    const int lr = lane & 15;
    const int lkg = (lane >> 4)*8;
    const int wr = wid >> 1, wc = wid & 1;
    const int b = bc >> 5;
    const int li = (bc & 31) * CHK;
    const unsigned short* xb = xT + (size_t)((b*NH + h)*HD)*SEQLEN + li;
    const unsigned short* sb = statesg + (size_t)blk * (HD*DSZ);
    const unsigned short* bb = bcbf + (size_t)r0*256;

    // stage 1: acc1 = C@B^T, acc2 = C@prev^T (B/prev frags direct global)
    f32x4 acc1[4][4], acc2[4][2];
    #pragma unroll
    for (int i=0;i<4;i++) {
        #pragma unroll
        for (int j=0;j<4;j++) acc1[i][j] = f32x4{0.f,0.f,0.f,0.f};
        #pragma unroll
        for (int j=0;j<2;j++) acc2[i][j] = f32x4{0.f,0.f,0.f,0.f};
    }
    #pragma unroll
    for (int k = 0; k < 4; k++) {
        bf16x8 a[4], bfr[4], pv[2];
        #pragma unroll
        for (int i=0;i<4;i++) a[i] = *(const bf16x8*)&P1[(wr*64 + i*16 + lr)*LDP + k*32 + lkg];
        #pragma unroll
        for (int j=0;j<4;j++) bfr[j] = *(const bf16x8*)(bb + (size_t)(wc*64 + j*16 + lr)*256 + k*32 + lkg);
        #pragma unroll
        for (int j=0;j<2;j++) pv[j] = *(const bf16x8*)(sb + (size_t)(wc*32 + j*16 + lr)*DSZ + k*32 + lkg);
        #pragma unroll
        for (int i=0;i<4;i++) {
            #pragma unroll
            for (int j=0;j<4;j++)
                acc1[i][j] = __builtin_amdgcn_mfma_f32_16x16x32_bf16(a[i], bfr[j], acc1[i][j], 0,0,0);
            #pragma unroll
            for (int j=0;j<2;j++)
                acc2[i][j] = __builtin_amdgcn_mfma_f32_16x16x32_bf16(a[i], pv[j], acc2[i][j], 0,0,0);
        }
    }
    __syncthreads();
    // M = CB * decay * dt (+ D on the diagonal) into P1
    const float Dv = Dg[h];
    const int cr = (lane >> 4)*4, cc = lane & 15;
    #pragma unroll
    for (int i=0;i<4;i++) {
        #pragma unroll
        for (int j=0;j<4;j++) {
            const int jj = wc*64 + j*16 + cc;
            #pragma unroll
            for (int r=0;r<4;r++) {
                const int ii = wr*64 + i*16 + cr + r;
                float v = 0.f;
                if (jj <= ii) v = acc1[i][j][r] * __expf(cum_s[ii] - cum_s[jj]) * dtc_s[jj];
                if (jj == ii) v += Dv;
                P1[ii*LDP + jj] = f2bf(v);
            }
        }
    }
    __syncthreads();
    // scale Y_off rows by exp(cum_i)
    #pragma unroll
    for (int i=0;i<4;i++) {
        #pragma unroll
        for (int r=0;r<4;r++) {
            const int ii = wr*64 + i*16 + cr + r;
            const float sc = __expf(cum_s[ii]);
            #pragma unroll
            for (int j=0;j<2;j++) acc2[i][j][r] *= sc;
        }
    }
    // stage 2: acc2 += (M + D*I) @ X  (X frags direct global)
    #pragma unroll
    for (int k = 0; k < 4; k++) {
        bf16x8 a[4], x2[2];
        #pragma unroll
        for (int i=0;i<4;i++) a[i] = *(const bf16x8*)&P1[(wr*64 + i*16 + lr)*LDP + k*32 + lkg];
        #pragma unroll
        for (int j=0;j<2;j++) x2[j] = *(const bf16x8*)(xb + (size_t)(wc*32 + j*16 + lr)*SEQLEN + k*32 + lkg);
        #pragma unroll
        for (int i=0;i<4;i++)
            #pragma unroll
            for (int j=0;j<2;j++)
                acc2[i][j] = __builtin_amdgcn_mfma_f32_16x16x32_bf16(a[i], x2[j], acc2[i][j], 0,0,0);
    }
    __syncthreads();   // all waves done reading P1
    // bounce y-tile (128 rows x 64 cols) through P1
    #pragma unroll
    for (int i=0;i<4;i++) {
        #pragma unroll
        for (int j=0;j<2;j++) {
            const int pp = wc*32 + j*16 + cc;
            #pragma unroll
            for (int r=0;r<4;r++) {
                const int ii = wr*64 + i*16 + cr + r;
                P1[ii*LDP + pp] = f2bf(acc2[i][j][r]);
            }
        }
    }
    __syncthreads();
    for (int i = t; i < 1024; i += 256) {   // 128 rows x 8 us8 groups
        const int ii = i >> 3, g = (i & 7)*8;
        *(us8*)&y[(size_t)(r0+ii)*DI + h*64 + g] = *(const us8*)&P1[ii*LDP + g];
    }
}

// ---------------- gate (y * silu(z)) + RMSNorm -> bf16 ----------------
__global__ __launch_bounds__(256) void gate_rms_kernel(
    const unsigned short* __restrict__ y, const unsigned short* __restrict__ z,
    const float* __restrict__ nw, unsigned short* __restrict__ tbf)
{
    const int row = blockIdx.x;
    const int t = threadIdx.x;
    const int lane = t & 63, wid = t >> 6;
    float tv[16];
    float ss = 0.f;
    #pragma unroll
    for (int i = 0; i < 2; i++) {
        const int c = (i*256 + t)*8;
        const us8 yv = *(const us8*)&y[(size_t)row*DI + c];
        const us8 zv = *(const us8*)&z[(size_t)row*DI + c];
        #pragma unroll
        for (int e = 0; e < 8; e++) {
            const float fy = bf2f(yv[e]);
            const float fz = bf2f(zv[e]);
            const float v = fy * (fz / (1.f + __expf(-fz)));
            tv[i*8+e] = v;
            ss += v*v;
        }
    }
    #pragma unroll
    for (int o = 1; o < 64; o <<= 1) ss += __shfl_xor(ss, o, 64);
    __shared__ float red[4];
    if (lane == 0) red[wid] = ss;
    __syncthreads();
    const float rms = rsqrtf((red[0]+red[1]+red[2]+red[3]) * (1.f/DI) + 1e-5f);
    #pragma unroll
    for (int i = 0; i < 2; i++) {
        const int c = (i*256 + t)*8;
        us8 o;
        #pragma unroll
        for (int e = 0; e < 8; e += 4) {
            const float4 wv = *(const float4*)&nw[c + e];
            o[e+0]=f2bf(tv[i*8+e+0]*rms*wv.x);
            o[e+1]=f2bf(tv[i*8+e+1]*rms*wv.y);
            o[e+2]=f2bf(tv[i*8+e+2]*rms*wv.z);
            o[e+3]=f2bf(tv[i*8+e+3]*rms*wv.w);
        }
        *(us8*)&tbf[(size_t)row*DI + c] = o;
    }
}

extern "C" void kernel_launch(void* const* d_in, const int* in_sizes, int n_in,
                              void* d_out, int out_size, void* d_ws, size_t ws_size,
                              hipStream_t stream)
{
    const float* u       = (const float*)d_in[0];
    const float* W_in    = (const float*)d_in[1];
    const float* conv_w  = (const float*)d_in[2];
    const float* conv_b  = (const float*)d_in[3];
    const float* dt_bias = (const float*)d_in[4];
    const float* A_log   = (const float*)d_in[5];
    const float* Dp      = (const float*)d_in[6];
    const float* norm_w  = (const float*)d_in[7];
    const float* W_out   = (const float*)d_in[8];
    float* out = (float*)d_out;

    char* ws = (char*)d_ws;
    const size_t OFF_WINT = 33554432;
    const size_t OFF_R2   = 68681728;
    const size_t OFF_R3   = 139984896;   // states (64M)
    const size_t OFF_SM   = 207093760;   // dtf 2M | cum 2M | bc_bf 4M | woutT 16M
    const size_t NEED     = OFF_SM + 2097152 + 2097152 + 4194304 + 16777216;
    if (ws_size < NEED) {   // diagnostic beacon: absmax ~= 10000 + ws_size_MB
        beacon_kernel<<<1, 64, 0, stream>>>(out, 10000.f + (float)(ws_size >> 20));
        return;
    }

    unsigned short* u_bf   = (unsigned short*)(ws);
    unsigned short* winT   = (unsigned short*)(ws + OFF_WINT);
    unsigned short* xTb    = (unsigned short*)(ws);
    unsigned short* t_bf   = (unsigned short*)(ws);
    unsigned short* xbc_bf = (unsigned short*)(ws + OFF_R2);
    unsigned short* y_bf   = (unsigned short*)(ws + OFF_R2);
    unsigned short* states = (unsigned short*)(ws + OFF_R3);
    float*          dtf    = (float*)(ws + OFF_SM);
    float*          cum    = (float*)(ws + OFF_SM + 2097152);
    unsigned short* bc_bf  = (unsigned short*)(ws + OFF_SM + 4194304);
    unsigned short* woutT  = (unsigned short*)(ws + OFF_SM + 8388608);
    unsigned short* z_bf   = (unsigned short*)d_out;   // 64MB, exact fit

    prep_kernel<<<PREP_CAST + PREP_TRA + PREP_TRB, 256, 0, stream>>>(
        u, u_bf, W_in, winT, W_out, woutT);
    gemm256<1><<<dim3(NBL/256, (DIPP+255)/256), 512, 0, stream>>>(
        u_bf, winT, nullptr, DM, 0, DIPP-1, z_bf, xbc_bf, dtf, dt_bias);
    conv_x_kernel<<<dim3(NBL/64, NH+5), 256, 0, stream>>>(
        xbc_bf, conv_w, conv_b, xTb, bc_bf, dtf, A_log, cum);
    ssm_passS<<<BATCH*NC*NH, 256, 0, stream>>>(bc_bf, xTb, cum, dtf, states);
    scan_kernel<<<4096, 256, 0, stream>>>(states, cum);
    ssm_passY<<<BATCH*NC*NH, 256, 0, stream>>>(bc_bf, xTb, states, cum, dtf, Dp, y_bf);
    gate_rms_kernel<<<NBL, 256, 0, stream>>>(y_bf, z_bf, norm_w, t_bf);
    gemm256<0><<<dim3(NBL/256, DM/256), 512, 0, stream>>>(
        t_bf, woutT, out, DI, DM, DM-1, nullptr, nullptr, nullptr, nullptr);
}